// Round 1
// baseline (1172.000 us; speedup 1.0000x reference)
//
#include <hip/hip_runtime.h>
#include <cstdint>

#define NN 100000
#define NE 1600000
#define NG 64
#define NH 128
#define NC 10
#define EPSV 1e-5f

constexpr int SCAN_BS = 256;
constexpr int SCAN_NB = (NN + SCAN_BS - 1) / SCAN_BS;   // 391

// ---------------- prep kernels ----------------

__global__ __launch_bounds__(256) void k_init(int* degE, int* counts) {
  int i = blockIdx.x * 256 + threadIdx.x;
  if (i < NN) degE[i] = 0;
  if (i < NG) counts[i] = 0;
}

__global__ __launch_bounds__(256) void k_deg(const int* __restrict__ ei,
                                             const int* __restrict__ batch,
                                             int* degE, int* counts) {
  int i = blockIdx.x * 256 + threadIdx.x;
  if (i < NE) atomicAdd(&degE[ei[NE + i]], 1);   // col = target
  if (i < NN) atomicAdd(&counts[batch[i]], 1);
}

__global__ __launch_bounds__(256) void k_dis(const int* __restrict__ degE, float* __restrict__ dis) {
  int i = blockIdx.x * 256 + threadIdx.x;
  if (i < NN) dis[i] = rsqrtf((float)(degE[i] + 1));   // +1 self-loop
}

__global__ __launch_bounds__(256) void k_scan1(const int* __restrict__ degE, int* __restrict__ offs,
                                               int* __restrict__ bsums) {
  __shared__ int sh[256];
  int t = threadIdx.x;
  int i = blockIdx.x * 256 + t;
  int v = (i < NN) ? degE[i] : 0;
  sh[t] = v;
  __syncthreads();
  for (int o = 1; o < 256; o <<= 1) {
    int x = (t >= o) ? sh[t - o] : 0;
    __syncthreads();
    sh[t] += x;
    __syncthreads();
  }
  if (i < NN) offs[i] = sh[t] - v;           // exclusive within block
  if (t == 255) bsums[blockIdx.x] = sh[255]; // block total
}

__global__ __launch_bounds__(512) void k_scan2(int* bsums, int nb) {
  __shared__ int sh[512];
  int t = threadIdx.x;
  int v = (t < nb) ? bsums[t] : 0;
  sh[t] = v;
  __syncthreads();
  for (int o = 1; o < 512; o <<= 1) {
    int x = (t >= o) ? sh[t - o] : 0;
    __syncthreads();
    sh[t] += x;
    __syncthreads();
  }
  if (t < nb) bsums[t] = sh[t] - v;          // exclusive block offsets
}

__global__ __launch_bounds__(256) void k_scan3(int* __restrict__ offs, const int* __restrict__ bsums,
                                               int* __restrict__ cursor) {
  int i = blockIdx.x * 256 + threadIdx.x;
  if (i >= NN) return;
  int o = offs[i] + bsums[blockIdx.x];
  offs[i] = o;
  cursor[i] = o;
}

__global__ __launch_bounds__(256) void k_fill(const int* __restrict__ ei, int* __restrict__ cursor,
                                              int* __restrict__ csr) {
  int e = blockIdx.x * 256 + threadIdx.x;
  if (e < NE) {
    int d = ei[NE + e];
    int p = atomicAdd(&cursor[d], 1);
    csr[p] = ei[e];                            // source node
  }
}

__global__ void k_gstart(const int* __restrict__ counts, int* __restrict__ gstart) {
  if (threadIdx.x == 0 && blockIdx.x == 0) {
    int s = 0;
    for (int g = 0; g < NG; ++g) { gstart[g] = s; s += counts[g]; }
    gstart[NG] = s;
  }
}

__global__ __launch_bounds__(256) void k_zero(float* p, int n) {
  int i = blockIdx.x * 256 + threadIdx.x;
  if (i < n) p[i] = 0.f;
}

// ---------------- GEMM: hs = (norm?(X) @ W) * dis ----------------
// 128-row tile, W (128x128) + X tile in LDS, 8x8 register micro-tile.
template <bool NORM>
__global__ __launch_bounds__(256) void k_gemm(const float* __restrict__ X, const float* __restrict__ W,
                                              const float* __restrict__ dis, const int* __restrict__ batch,
                                              const float* __restrict__ Aaff, const float* __restrict__ Baff,
                                              float* __restrict__ out) {
  __shared__ float ws_[128][128];
  __shared__ float xs[128][129];    // +1 pad: per-k row reads conflict-free
  int t = threadIdx.x;
  int row0 = blockIdx.x * 128;

#pragma unroll
  for (int i = 0; i < 16; ++i) {    // stage W: 4096 float4
    int idx4 = i * 256 + t;
    int k = idx4 >> 5, c4 = idx4 & 31;
    float4 v = reinterpret_cast<const float4*>(W)[idx4];
    *reinterpret_cast<float4*>(&ws_[k][c4 * 4]) = v;
  }
#pragma unroll
  for (int i = 0; i < 16; ++i) {    // stage X tile (optionally graph-norm affine)
    int idx4 = i * 256 + t;
    int r = idx4 >> 5, c4 = idx4 & 31;
    int grow = row0 + r;
    float4 v = make_float4(0.f, 0.f, 0.f, 0.f);
    if (grow < NN) {
      v = reinterpret_cast<const float4*>(X)[(size_t)grow * 32 + c4];
      if (NORM) {
        int g = batch[grow];
        int k0 = c4 * 4;
        const float* Ag = Aaff + g * NH;
        const float* Bg = Baff + g * NH;
        v.x = fmaf(Ag[k0 + 0], v.x, Bg[k0 + 0]);
        v.y = fmaf(Ag[k0 + 1], v.y, Bg[k0 + 1]);
        v.z = fmaf(Ag[k0 + 2], v.z, Bg[k0 + 2]);
        v.w = fmaf(Ag[k0 + 3], v.w, Bg[k0 + 3]);
      }
    }
    xs[r][c4 * 4 + 0] = v.x;
    xs[r][c4 * 4 + 1] = v.y;
    xs[r][c4 * 4 + 2] = v.z;
    xs[r][c4 * 4 + 3] = v.w;
  }
  __syncthreads();

  int cg = t & 15, rg = t >> 4;     // 16 col-groups x 16 row-groups
  float acc[8][8];
#pragma unroll
  for (int a = 0; a < 8; ++a)
#pragma unroll
    for (int b = 0; b < 8; ++b) acc[a][b] = 0.f;

#pragma unroll 4
  for (int k = 0; k < 128; ++k) {
    float xv[8];
#pragma unroll
    for (int j = 0; j < 8; ++j) xv[j] = xs[rg * 8 + j][k];
    float4 w0 = *reinterpret_cast<const float4*>(&ws_[k][cg * 8]);
    float4 w1 = *reinterpret_cast<const float4*>(&ws_[k][cg * 8 + 4]);
    float wv[8] = {w0.x, w0.y, w0.z, w0.w, w1.x, w1.y, w1.z, w1.w};
#pragma unroll
    for (int j = 0; j < 8; ++j)
#pragma unroll
      for (int c = 0; c < 8; ++c) acc[j][c] = fmaf(xv[j], wv[c], acc[j][c]);
  }

#pragma unroll
  for (int j = 0; j < 8; ++j) {
    int grow = row0 + rg * 8 + j;
    if (grow >= NN) break;
    float d = dis[grow];
    float4 o0 = make_float4(acc[j][0] * d, acc[j][1] * d, acc[j][2] * d, acc[j][3] * d);
    float4 o1 = make_float4(acc[j][4] * d, acc[j][5] * d, acc[j][6] * d, acc[j][7] * d);
    float4* op = reinterpret_cast<float4*>(out + (size_t)grow * NH + cg * 8);
    op[0] = o0;
    op[1] = o1;
  }
}

// ---------------- aggregation: t = relu(dis[i]*(hs[i]+sum_src hs[src]) + b) ----------------
__global__ __launch_bounds__(256) void k_agg(const float* __restrict__ hs, const int* __restrict__ offs,
                                             const int* __restrict__ degE, const int* __restrict__ csr,
                                             const float* __restrict__ dis, const float* __restrict__ bias,
                                             float* __restrict__ out) {
  int wv = threadIdx.x >> 6, lane = threadIdx.x & 63;
  int node = blockIdx.x * 4 + wv;
  if (node >= NN) return;
  const float2* hs2 = reinterpret_cast<const float2*>(hs);
  float2 acc = hs2[(size_t)node * 64 + lane];   // self term (hs already has dis[src])
  int beg = offs[node], cnt = degE[node];
  int i = 0;
  for (; i + 4 <= cnt; i += 4) {
    int s0 = csr[beg + i], s1 = csr[beg + i + 1], s2 = csr[beg + i + 2], s3 = csr[beg + i + 3];
    float2 v0 = hs2[(size_t)s0 * 64 + lane];
    float2 v1 = hs2[(size_t)s1 * 64 + lane];
    float2 v2 = hs2[(size_t)s2 * 64 + lane];
    float2 v3 = hs2[(size_t)s3 * 64 + lane];
    acc.x += v0.x + v1.x + v2.x + v3.x;
    acc.y += v0.y + v1.y + v2.y + v3.y;
  }
  for (; i < cnt; ++i) {
    int s = csr[beg + i];
    float2 v = hs2[(size_t)s * 64 + lane];
    acc.x += v.x;
    acc.y += v.y;
  }
  float d = dis[node];
  int f = lane * 2;
  float ox = fmaxf(fmaf(d, acc.x, bias[f]), 0.f);
  float oy = fmaxf(fmaf(d, acc.y, bias[f + 1]), 0.f);
  reinterpret_cast<float2*>(out)[(size_t)node * 64 + lane] = make_float2(ox, oy);
}

// ---------------- GraphNorm stats: per-(g,f) sum & sumsq ----------------
__global__ __launch_bounds__(256) void k_stats(const float* __restrict__ t1, const int* __restrict__ gstart,
                                               float* __restrict__ acc) {
  int g = blockIdx.x >> 4, s = blockIdx.x & 15;   // 16 slices per graph
  int beg = gstart[g], end = gstart[g + 1];
  int f = threadIdx.x & 127, half = threadIdx.x >> 7;
  float sum = 0.f, sq = 0.f;
  for (int n = beg + s * 2 + half; n < end; n += 32) {
    float v = t1[(size_t)n * NH + f];
    sum += v;
    sq = fmaf(v, v, sq);
  }
  __shared__ float sh[2][128];
  if (half) { sh[0][f] = sum; sh[1][f] = sq; }
  __syncthreads();
  if (!half) {
    sum += sh[0][f];
    sq += sh[1][f];
    atomicAdd(&acc[g * NH + f], sum);
    atomicAdd(&acc[NG * NH + g * NH + f], sq);
  }
}

// layer-1 finalize: affine A*v+B implementing gw*(v - ga*m)*rstd + gb
__global__ __launch_bounds__(128) void k_fin1(const float* __restrict__ acc, const int* __restrict__ counts,
                                              const float* __restrict__ gw, const float* __restrict__ gb,
                                              const float* __restrict__ ga,
                                              float* __restrict__ Aaff, float* __restrict__ Baff) {
  int g = blockIdx.x, f = threadIdx.x;
  float cnt = fmaxf((float)counts[g], 1.f);
  float m = acc[g * NH + f] / cnt;
  float ex2 = acc[NG * NH + g * NH + f] / cnt;
  float a = ga[f];
  float var = ex2 - 2.f * a * m * m + a * a * m * m;
  float rstd = rsqrtf(var + EPSV);
  float A = gw[f] * rstd;
  Aaff[g * NH + f] = A;
  Baff[g * NH + f] = gb[f] - A * a * m;
}

// layer-2 finalize: pooled = mean(norm out) = gw*rstd*m*(1-ga) + gb  (no per-node pass!)
__global__ __launch_bounds__(128) void k_fin2(const float* __restrict__ acc, const int* __restrict__ counts,
                                              const float* __restrict__ gw, const float* __restrict__ gb,
                                              const float* __restrict__ ga,
                                              float* __restrict__ pooled) {
  int g = blockIdx.x, f = threadIdx.x;
  float cnt = fmaxf((float)counts[g], 1.f);
  float m = acc[g * NH + f] / cnt;
  float ex2 = acc[NG * NH + g * NH + f] / cnt;
  float a = ga[f];
  float var = ex2 - 2.f * a * m * m + a * a * m * m;
  float rstd = rsqrtf(var + EPSV);
  pooled[g * NH + f] = gw[f] * rstd * (m - a * m) + gb[f];
}

// ---------------- head: logits + softmax ----------------
__global__ __launch_bounds__(64) void k_head(const float* __restrict__ pooled, const float* __restrict__ Wc,
                                             const float* __restrict__ bc, float* __restrict__ outp) {
  int g = blockIdx.x, t = threadIdx.x;
  __shared__ float lg[NC];
  if (t < NC) {
    float s = bc[t];
    for (int h = 0; h < NH; ++h) s = fmaf(pooled[g * NH + h], Wc[h * NC + t], s);
    lg[t] = s;
  }
  __syncthreads();
  if (t == 0) {
    float mx = lg[0];
    for (int c = 1; c < NC; ++c) mx = fmaxf(mx, lg[c]);
    float ex[NC];
    float sum = 0.f;
    for (int c = 0; c < NC; ++c) { ex[c] = __expf(lg[c] - mx); sum += ex[c]; }
    float inv = 1.f / sum;
    for (int c = 0; c < NC; ++c) outp[g * NC + c] = ex[c] * inv;
  }
}

// ---------------- launch ----------------
extern "C" void kernel_launch(void* const* d_in, const int* in_sizes, int n_in,
                              void* d_out, int out_size, void* d_ws, size_t ws_size,
                              hipStream_t stream) {
  const float* x   = (const float*)d_in[0];
  const int*   ei  = (const int*)d_in[1];
  const int*   bat = (const int*)d_in[2];
  const float* W1  = (const float*)d_in[3];
  const float* b1  = (const float*)d_in[4];
  const float* gw1 = (const float*)d_in[5];
  const float* gb1 = (const float*)d_in[6];
  const float* ga1 = (const float*)d_in[7];
  const float* W2  = (const float*)d_in[8];
  const float* b2  = (const float*)d_in[9];
  const float* gw2 = (const float*)d_in[10];
  const float* gb2 = (const float*)d_in[11];
  const float* ga2 = (const float*)d_in[12];
  const float* Wc  = (const float*)d_in[13];
  const float* bc  = (const float*)d_in[14];
  float* outp = (float*)d_out;

  char* ws = (char*)d_ws;
  size_t off = 0;
  auto alloc = [&](size_t b) { size_t p = off; off += (b + 255) & ~(size_t)255; return p; };
  int*   degE    = (int*)(ws + alloc((size_t)NN * 4));
  float* dis     = (float*)(ws + alloc((size_t)NN * 4));
  int*   counts  = (int*)(ws + alloc(NG * 4));
  int*   gstart  = (int*)(ws + alloc((NG + 1) * 4));
  int*   offs    = (int*)(ws + alloc((size_t)NN * 4));
  int*   cursor  = (int*)(ws + alloc((size_t)NN * 4));
  int*   bsums   = (int*)(ws + alloc(512 * 4));
  int*   csr     = (int*)(ws + alloc((size_t)NE * 4));
  float* statacc = (float*)(ws + alloc((size_t)2 * NG * NH * 4));
  float* Aaff    = (float*)(ws + alloc((size_t)NG * NH * 4));
  float* Baff    = (float*)(ws + alloc((size_t)NG * NH * 4));
  float* pooled  = (float*)(ws + alloc((size_t)NG * NH * 4));
  float* bufA    = (float*)(ws + alloc((size_t)NN * NH * 4));
  float* bufB    = (float*)(ws + alloc((size_t)NN * NH * 4));
  (void)ws_size; (void)in_sizes; (void)n_in; (void)out_size;

  int nb256 = (NN + 255) / 256;   // 391
  int nbE   = (NE + 255) / 256;   // 6250
  int nstat = 2 * NG * NH;

  k_init<<<nb256, 256, 0, stream>>>(degE, counts);
  k_deg<<<nbE, 256, 0, stream>>>(ei, bat, degE, counts);
  k_dis<<<nb256, 256, 0, stream>>>(degE, dis);
  k_scan1<<<SCAN_NB, 256, 0, stream>>>(degE, offs, bsums);
  k_scan2<<<1, 512, 0, stream>>>(bsums, SCAN_NB);
  k_scan3<<<SCAN_NB, 256, 0, stream>>>(offs, bsums, cursor);
  k_fill<<<nbE, 256, 0, stream>>>(ei, cursor, csr);
  k_gstart<<<1, 64, 0, stream>>>(counts, gstart);

  // layer 1
  k_zero<<<(nstat + 255) / 256, 256, 0, stream>>>(statacc, nstat);
  k_gemm<false><<<(NN + 127) / 128, 256, 0, stream>>>(x, W1, dis, bat, nullptr, nullptr, bufA);
  k_agg<<<(NN + 3) / 4, 256, 0, stream>>>(bufA, offs, degE, csr, dis, b1, bufB);
  k_stats<<<NG * 16, 256, 0, stream>>>(bufB, gstart, statacc);
  k_fin1<<<NG, 128, 0, stream>>>(statacc, counts, gw1, gb1, ga1, Aaff, Baff);

  // layer 2 (norm fused into GEMM input staging)
  k_zero<<<(nstat + 255) / 256, 256, 0, stream>>>(statacc, nstat);
  k_gemm<true><<<(NN + 127) / 128, 256, 0, stream>>>(bufB, W2, dis, bat, Aaff, Baff, bufA);
  k_agg<<<(NN + 3) / 4, 256, 0, stream>>>(bufA, offs, degE, csr, dis, b2, bufB);
  k_stats<<<NG * 16, 256, 0, stream>>>(bufB, gstart, statacc);
  k_fin2<<<NG, 128, 0, stream>>>(statacc, counts, gw2, gb2, ga2, pooled);

  k_head<<<NG, 64, 0, stream>>>(pooled, Wc, bc, outp);
}

// Round 2
// 522.351 us; speedup vs baseline: 2.2437x; 2.2437x over previous
//
#include <hip/hip_runtime.h>
#include <cstdint>

#define NN 100000
#define NE 1600000
#define NG 64
#define NH 128
#define NC 10
#define EPSV 1e-5f

#define NB 782                       // (NN+127)>>7 coarse buckets (128 nodes each)
#define NBLK 512                     // histogram/scatter blocks
#define EPB ((NE + NBLK - 1) / NBLK) // 3125 edges per block
#define NSCAN (NB * NBLK)            // 400384, divisible by 1024
#define NSB (NSCAN / 1024)           // 391 scan blocks

// ---------------- graph prep: counting sort by destination ----------------

__global__ __launch_bounds__(128) void k_gstart2(const int* __restrict__ batch,
                                                 int* __restrict__ gstart, int* __restrict__ counts) {
  __shared__ int lb[NG + 1];
  int t = threadIdx.x;
  if (t <= NG) {                      // first index with batch[i] >= t (batch is sorted)
    int lo = 0, hi = NN;
    while (lo < hi) { int mid = (lo + hi) >> 1; if (batch[mid] < t) lo = mid + 1; else hi = mid; }
    lb[t] = lo;
  }
  __syncthreads();
  if (t < NG) { gstart[t] = lb[t]; counts[t] = lb[t + 1] - lb[t]; }
  if (t == 0) gstart[NG] = NN;
}

__global__ __launch_bounds__(256) void k_hist(const int* __restrict__ ei, int* __restrict__ ghist) {
  __shared__ int h[NB];
  int t = threadIdx.x, blk = blockIdx.x;
  for (int i = t; i < NB; i += 256) h[i] = 0;
  __syncthreads();
  int e0 = blk * EPB, e1 = min(NE, e0 + EPB);
  for (int e = e0 + t; e < e1; e += 256) atomicAdd(&h[ei[NE + e] >> 7], 1);
  __syncthreads();
  for (int i = t; i < NB; i += 256) ghist[i * NBLK + blk] = h[i];
}

__global__ __launch_bounds__(256) void k_scan1g(int* __restrict__ data, int* __restrict__ bsums) {
  __shared__ int sh[256];
  int t = threadIdx.x;
  int base = blockIdx.x * 1024 + t * 4;
  int4 v = *reinterpret_cast<const int4*>(data + base);
  int s = v.x + v.y + v.z + v.w;
  sh[t] = s;
  __syncthreads();
  for (int o = 1; o < 256; o <<= 1) {
    int x = (t >= o) ? sh[t - o] : 0;
    __syncthreads();
    sh[t] += x;
    __syncthreads();
  }
  int ex = sh[t] - s;
  int4 o4;
  o4.x = ex; o4.y = ex + v.x; o4.z = ex + v.x + v.y; o4.w = ex + v.x + v.y + v.z;
  *reinterpret_cast<int4*>(data + base) = o4;
  if (t == 255) bsums[blockIdx.x] = sh[255];
}

__global__ __launch_bounds__(512) void k_scan2(int* bsums, int nb) {
  __shared__ int sh[512];
  int t = threadIdx.x;
  int v = (t < nb) ? bsums[t] : 0;
  sh[t] = v;
  __syncthreads();
  for (int o = 1; o < 512; o <<= 1) {
    int x = (t >= o) ? sh[t - o] : 0;
    __syncthreads();
    sh[t] += x;
    __syncthreads();
  }
  if (t < nb) bsums[t] = sh[t] - v;   // exclusive
}

__global__ __launch_bounds__(256) void k_scan3g(int* __restrict__ data, const int* __restrict__ bsums) {
  int t = threadIdx.x;
  int base = blockIdx.x * 1024 + t * 4;
  int add = bsums[blockIdx.x];
  int4 v = *reinterpret_cast<int4*>(data + base);
  v.x += add; v.y += add; v.z += add; v.w += add;
  *reinterpret_cast<int4*>(data + base) = v;
}

__global__ __launch_bounds__(256) void k_scatter(const int* __restrict__ ei, const int* __restrict__ ghist,
                                                 int2* __restrict__ tmp) {
  __shared__ int cur[NB];
  int t = threadIdx.x, blk = blockIdx.x;
  for (int i = t; i < NB; i += 256) cur[i] = ghist[i * NBLK + blk];
  __syncthreads();
  int e0 = blk * EPB, e1 = min(NE, e0 + EPB);
  for (int e = e0 + t; e < e1; e += 256) {
    int d = ei[NE + e], s = ei[e];
    int p = atomicAdd(&cur[d >> 7], 1);   // LDS atomic (fast, block-local)
    tmp[p] = make_int2(d, s);
  }
}

__global__ __launch_bounds__(256) void k_fine(const int2* __restrict__ tmp, const int* __restrict__ ghist,
                                              int* __restrict__ deg, int* __restrict__ offs,
                                              float* __restrict__ dis, int* __restrict__ csr) {
  __shared__ int fh[128], fsc[128], fc[128];
  int b = blockIdx.x, t = threadIdx.x;
  int bs = ghist[b * NBLK];
  int be = (b + 1 < NB) ? ghist[(b + 1) * NBLK] : NE;
  if (t < 128) fh[t] = 0;
  __syncthreads();
  for (int e = bs + t; e < be; e += 256) atomicAdd(&fh[tmp[e].x & 127], 1);
  __syncthreads();
  if (t < 128) fsc[t] = fh[t];
  __syncthreads();
  for (int o = 1; o < 128; o <<= 1) {
    int x = 0;
    if (t < 128 && t >= o) x = fsc[t - o];
    __syncthreads();
    if (t < 128) fsc[t] += x;
    __syncthreads();
  }
  if (t < 128) {
    int ex = fsc[t] - fh[t];
    int node = b * 128 + t;
    fc[t] = bs + ex;
    if (node < NN) {
      deg[node] = fh[t];
      offs[node] = bs + ex;
      dis[node] = rsqrtf((float)(fh[t] + 1));   // +1 self-loop
    }
  }
  __syncthreads();
  for (int e = bs + t; e < be; e += 256) {
    int2 ds = tmp[e];
    int p = atomicAdd(&fc[ds.x & 127], 1);
    csr[p] = ds.y;
  }
}

__global__ __launch_bounds__(256) void k_zero(float* p, int n) {
  int i = blockIdx.x * 256 + threadIdx.x;
  if (i < n) p[i] = 0.f;
}

// ---------------- GEMM: hs = (norm?(X) @ W) * dis ----------------
template <bool NORM>
__global__ __launch_bounds__(256) void k_gemm(const float* __restrict__ X, const float* __restrict__ W,
                                              const float* __restrict__ dis, const int* __restrict__ batch,
                                              const float* __restrict__ Aaff, const float* __restrict__ Baff,
                                              float* __restrict__ out) {
  __shared__ float ws_[128][128];
  __shared__ float xs[128][129];
  int t = threadIdx.x;
  int row0 = blockIdx.x * 128;

#pragma unroll
  for (int i = 0; i < 16; ++i) {
    int idx4 = i * 256 + t;
    int k = idx4 >> 5, c4 = idx4 & 31;
    float4 v = reinterpret_cast<const float4*>(W)[idx4];
    *reinterpret_cast<float4*>(&ws_[k][c4 * 4]) = v;
  }
#pragma unroll
  for (int i = 0; i < 16; ++i) {
    int idx4 = i * 256 + t;
    int r = idx4 >> 5, c4 = idx4 & 31;
    int grow = row0 + r;
    float4 v = make_float4(0.f, 0.f, 0.f, 0.f);
    if (grow < NN) {
      v = reinterpret_cast<const float4*>(X)[(size_t)grow * 32 + c4];
      if (NORM) {
        int g = batch[grow];
        int k0 = c4 * 4;
        const float* Ag = Aaff + g * NH;
        const float* Bg = Baff + g * NH;
        v.x = fmaf(Ag[k0 + 0], v.x, Bg[k0 + 0]);
        v.y = fmaf(Ag[k0 + 1], v.y, Bg[k0 + 1]);
        v.z = fmaf(Ag[k0 + 2], v.z, Bg[k0 + 2]);
        v.w = fmaf(Ag[k0 + 3], v.w, Bg[k0 + 3]);
      }
    }
    xs[r][c4 * 4 + 0] = v.x;
    xs[r][c4 * 4 + 1] = v.y;
    xs[r][c4 * 4 + 2] = v.z;
    xs[r][c4 * 4 + 3] = v.w;
  }
  __syncthreads();

  int cg = t & 15, rg = t >> 4;
  float acc[8][8];
#pragma unroll
  for (int a = 0; a < 8; ++a)
#pragma unroll
    for (int b = 0; b < 8; ++b) acc[a][b] = 0.f;

#pragma unroll 4
  for (int k = 0; k < 128; ++k) {
    float xv[8];
#pragma unroll
    for (int j = 0; j < 8; ++j) xv[j] = xs[rg * 8 + j][k];
    float4 w0 = *reinterpret_cast<const float4*>(&ws_[k][cg * 8]);
    float4 w1 = *reinterpret_cast<const float4*>(&ws_[k][cg * 8 + 4]);
    float wv[8] = {w0.x, w0.y, w0.z, w0.w, w1.x, w1.y, w1.z, w1.w};
#pragma unroll
    for (int j = 0; j < 8; ++j)
#pragma unroll
      for (int c = 0; c < 8; ++c) acc[j][c] = fmaf(xv[j], wv[c], acc[j][c]);
  }

#pragma unroll
  for (int j = 0; j < 8; ++j) {
    int grow = row0 + rg * 8 + j;
    if (grow >= NN) break;
    float d = dis[grow];
    float4 o0 = make_float4(acc[j][0] * d, acc[j][1] * d, acc[j][2] * d, acc[j][3] * d);
    float4 o1 = make_float4(acc[j][4] * d, acc[j][5] * d, acc[j][6] * d, acc[j][7] * d);
    float4* op = reinterpret_cast<float4*>(out + (size_t)grow * NH + cg * 8);
    op[0] = o0;
    op[1] = o1;
  }
}

// ---------------- aggregation: t = relu(dis[i]*(hs[i]+sum_src hs[src]) + b) ----------------
__global__ __launch_bounds__(256) void k_agg(const float* __restrict__ hs, const int* __restrict__ offs,
                                             const int* __restrict__ deg, const int* __restrict__ csr,
                                             const float* __restrict__ dis, const float* __restrict__ bias,
                                             float* __restrict__ out) {
  int wv = threadIdx.x >> 6, lane = threadIdx.x & 63;
  int node = blockIdx.x * 4 + wv;
  if (node >= NN) return;
  const float2* hs2 = reinterpret_cast<const float2*>(hs);
  float2 acc = hs2[(size_t)node * 64 + lane];   // self term (hs already has dis[src])
  int beg = offs[node], cnt = deg[node];
  int i = 0;
  for (; i + 4 <= cnt; i += 4) {
    int s0 = csr[beg + i], s1 = csr[beg + i + 1], s2 = csr[beg + i + 2], s3 = csr[beg + i + 3];
    float2 v0 = hs2[(size_t)s0 * 64 + lane];
    float2 v1 = hs2[(size_t)s1 * 64 + lane];
    float2 v2 = hs2[(size_t)s2 * 64 + lane];
    float2 v3 = hs2[(size_t)s3 * 64 + lane];
    acc.x += v0.x + v1.x + v2.x + v3.x;
    acc.y += v0.y + v1.y + v2.y + v3.y;
  }
  for (; i < cnt; ++i) {
    int s = csr[beg + i];
    float2 v = hs2[(size_t)s * 64 + lane];
    acc.x += v.x;
    acc.y += v.y;
  }
  float d = dis[node];
  int f = lane * 2;
  float ox = fmaxf(fmaf(d, acc.x, bias[f]), 0.f);
  float oy = fmaxf(fmaf(d, acc.y, bias[f + 1]), 0.f);
  reinterpret_cast<float2*>(out)[(size_t)node * 64 + lane] = make_float2(ox, oy);
}

// ---------------- GraphNorm stats: per-(g,f) sum & sumsq ----------------
__global__ __launch_bounds__(256) void k_stats(const float* __restrict__ t1, const int* __restrict__ gstart,
                                               float* __restrict__ acc) {
  int g = blockIdx.x >> 4, s = blockIdx.x & 15;
  int beg = gstart[g], end = gstart[g + 1];
  int f = threadIdx.x & 127, half = threadIdx.x >> 7;
  float sum = 0.f, sq = 0.f;
  for (int n = beg + s * 2 + half; n < end; n += 32) {
    float v = t1[(size_t)n * NH + f];
    sum += v;
    sq = fmaf(v, v, sq);
  }
  __shared__ float sh[2][128];
  if (half) { sh[0][f] = sum; sh[1][f] = sq; }
  __syncthreads();
  if (!half) {
    sum += sh[0][f];
    sq += sh[1][f];
    atomicAdd(&acc[g * NH + f], sum);
    atomicAdd(&acc[NG * NH + g * NH + f], sq);
  }
}

__global__ __launch_bounds__(128) void k_fin1(const float* __restrict__ acc, const int* __restrict__ counts,
                                              const float* __restrict__ gw, const float* __restrict__ gb,
                                              const float* __restrict__ ga,
                                              float* __restrict__ Aaff, float* __restrict__ Baff) {
  int g = blockIdx.x, f = threadIdx.x;
  float cnt = fmaxf((float)counts[g], 1.f);
  float m = acc[g * NH + f] / cnt;
  float ex2 = acc[NG * NH + g * NH + f] / cnt;
  float a = ga[f];
  float var = ex2 - 2.f * a * m * m + a * a * m * m;
  float rstd = rsqrtf(var + EPSV);
  float A = gw[f] * rstd;
  Aaff[g * NH + f] = A;
  Baff[g * NH + f] = gb[f] - A * a * m;
}

__global__ __launch_bounds__(128) void k_fin2(const float* __restrict__ acc, const int* __restrict__ counts,
                                              const float* __restrict__ gw, const float* __restrict__ gb,
                                              const float* __restrict__ ga,
                                              float* __restrict__ pooled) {
  int g = blockIdx.x, f = threadIdx.x;
  float cnt = fmaxf((float)counts[g], 1.f);
  float m = acc[g * NH + f] / cnt;
  float ex2 = acc[NG * NH + g * NH + f] / cnt;
  float a = ga[f];
  float var = ex2 - 2.f * a * m * m + a * a * m * m;
  float rstd = rsqrtf(var + EPSV);
  pooled[g * NH + f] = gw[f] * rstd * (m - a * m) + gb[f];
}

__global__ __launch_bounds__(64) void k_head(const float* __restrict__ pooled, const float* __restrict__ Wc,
                                             const float* __restrict__ bc, float* __restrict__ outp) {
  int g = blockIdx.x, t = threadIdx.x;
  __shared__ float lg[NC];
  if (t < NC) {
    float s = bc[t];
    for (int h = 0; h < NH; ++h) s = fmaf(pooled[g * NH + h], Wc[h * NC + t], s);
    lg[t] = s;
  }
  __syncthreads();
  if (t == 0) {
    float mx = lg[0];
    for (int c = 1; c < NC; ++c) mx = fmaxf(mx, lg[c]);
    float ex[NC];
    float sum = 0.f;
    for (int c = 0; c < NC; ++c) { ex[c] = __expf(lg[c] - mx); sum += ex[c]; }
    float inv = 1.f / sum;
    for (int c = 0; c < NC; ++c) outp[g * NC + c] = ex[c] * inv;
  }
}

// ---------------- launch ----------------
extern "C" void kernel_launch(void* const* d_in, const int* in_sizes, int n_in,
                              void* d_out, int out_size, void* d_ws, size_t ws_size,
                              hipStream_t stream) {
  const float* x   = (const float*)d_in[0];
  const int*   ei  = (const int*)d_in[1];
  const int*   bat = (const int*)d_in[2];
  const float* W1  = (const float*)d_in[3];
  const float* b1  = (const float*)d_in[4];
  const float* gw1 = (const float*)d_in[5];
  const float* gb1 = (const float*)d_in[6];
  const float* ga1 = (const float*)d_in[7];
  const float* W2  = (const float*)d_in[8];
  const float* b2  = (const float*)d_in[9];
  const float* gw2 = (const float*)d_in[10];
  const float* gb2 = (const float*)d_in[11];
  const float* ga2 = (const float*)d_in[12];
  const float* Wc  = (const float*)d_in[13];
  const float* bc  = (const float*)d_in[14];
  float* outp = (float*)d_out;

  char* ws = (char*)d_ws;
  size_t off = 0;
  auto alloc = [&](size_t b) { size_t p = off; off += (b + 255) & ~(size_t)255; return p; };
  int*   deg     = (int*)(ws + alloc((size_t)NN * 4));
  float* dis     = (float*)(ws + alloc((size_t)NN * 4));
  int*   counts  = (int*)(ws + alloc(NG * 4));
  int*   gstart  = (int*)(ws + alloc((NG + 1) * 4));
  int*   offs    = (int*)(ws + alloc((size_t)NN * 4));
  int*   bsums   = (int*)(ws + alloc(512 * 4));
  int*   csr     = (int*)(ws + alloc((size_t)NE * 4));
  float* statacc = (float*)(ws + alloc((size_t)2 * NG * NH * 4));
  float* Aaff    = (float*)(ws + alloc((size_t)NG * NH * 4));
  float* Baff    = (float*)(ws + alloc((size_t)NG * NH * 4));
  float* pooled  = (float*)(ws + alloc((size_t)NG * NH * 4));
  float* bufA    = (float*)(ws + alloc((size_t)NN * NH * 4));
  float* bufB    = (float*)(ws + alloc((size_t)NN * NH * 4));
  // sort temps alias bufA (dead before first k_gemm writes bufA)
  int2* tmp   = (int2*)bufA;                                        // 12.8 MB
  int*  ghist = (int*)((char*)bufA + (((size_t)NE * 8 + 255) & ~(size_t)255)); // 1.6 MB
  (void)ws_size; (void)in_sizes; (void)n_in; (void)out_size;

  int nstat = 2 * NG * NH;

  // prep: counts/gstart via binary search (batch sorted); CSR via counting sort
  k_gstart2<<<1, 128, 0, stream>>>(bat, gstart, counts);
  k_hist<<<NBLK, 256, 0, stream>>>(ei, ghist);
  k_scan1g<<<NSB, 256, 0, stream>>>(ghist, bsums);
  k_scan2<<<1, 512, 0, stream>>>(bsums, NSB);
  k_scan3g<<<NSB, 256, 0, stream>>>(ghist, bsums);
  k_scatter<<<NBLK, 256, 0, stream>>>(ei, ghist, tmp);
  k_fine<<<NB, 256, 0, stream>>>(tmp, ghist, deg, offs, dis, csr);

  // layer 1
  k_zero<<<(nstat + 255) / 256, 256, 0, stream>>>(statacc, nstat);
  k_gemm<false><<<(NN + 127) / 128, 256, 0, stream>>>(x, W1, dis, bat, nullptr, nullptr, bufA);
  k_agg<<<(NN + 3) / 4, 256, 0, stream>>>(bufA, offs, deg, csr, dis, b1, bufB);
  k_stats<<<NG * 16, 256, 0, stream>>>(bufB, gstart, statacc);
  k_fin1<<<NG, 128, 0, stream>>>(statacc, counts, gw1, gb1, ga1, Aaff, Baff);

  // layer 2 (norm fused into GEMM input staging)
  k_zero<<<(nstat + 255) / 256, 256, 0, stream>>>(statacc, nstat);
  k_gemm<true><<<(NN + 127) / 128, 256, 0, stream>>>(bufB, W2, dis, bat, Aaff, Baff, bufA);
  k_agg<<<(NN + 3) / 4, 256, 0, stream>>>(bufA, offs, deg, csr, dis, b2, bufB);
  k_stats<<<NG * 16, 256, 0, stream>>>(bufB, gstart, statacc);
  k_fin2<<<NG, 128, 0, stream>>>(statacc, counts, gw2, gb2, ga2, pooled);

  k_head<<<NG, 64, 0, stream>>>(pooled, Wc, bc, outp);
}

// Round 3
// 282.468 us; speedup vs baseline: 4.1491x; 1.8492x over previous
//
#include <hip/hip_runtime.h>
#include <cstdint>

#define NN 100000
#define NE 1600000
#define NG 64
#define NH 128
#define NC 10
#define EPSV 1e-5f

#define NB 782                       // (NN+127)>>7 coarse buckets (128 nodes each)
#define NBLK 512                     // histogram/scatter blocks
#define EPB ((NE + NBLK - 1) / NBLK) // 3125 edges per block
#define NSCAN (NB * NBLK)            // 400384, divisible by 1024
#define NSB (NSCAN / 1024)           // 391 scan blocks

typedef __attribute__((ext_vector_type(8))) short bf16x8;
typedef __attribute__((ext_vector_type(4))) float f32x4;

__device__ __forceinline__ ushort f2b(float f) {
  uint u = __builtin_bit_cast(uint, f);
  u = (u + 0x7FFFu + ((u >> 16) & 1u)) >> 16;
  return (ushort)u;
}
__device__ __forceinline__ float b2f(ushort h) {
  return __builtin_bit_cast(float, ((uint)h) << 16);
}
__device__ __forceinline__ float lo2f(uint v) { return __builtin_bit_cast(float, v << 16); }
__device__ __forceinline__ float hi2f(uint v) { return __builtin_bit_cast(float, v & 0xFFFF0000u); }

// ---------------- graph prep: counting sort by destination ----------------

__global__ __launch_bounds__(128) void k_gstart2(const int* __restrict__ batch,
                                                 int* __restrict__ gstart, int* __restrict__ counts) {
  __shared__ int lb[NG + 1];
  int t = threadIdx.x;
  if (t <= NG) {                      // first index with batch[i] >= t (batch is sorted)
    int lo = 0, hi = NN;
    while (lo < hi) { int mid = (lo + hi) >> 1; if (batch[mid] < t) lo = mid + 1; else hi = mid; }
    lb[t] = lo;
  }
  __syncthreads();
  if (t < NG) { gstart[t] = lb[t]; counts[t] = lb[t + 1] - lb[t]; }
  if (t == 0) gstart[NG] = NN;
}

__global__ __launch_bounds__(256) void k_hist(const int* __restrict__ ei, int* __restrict__ ghist) {
  __shared__ int h[NB];
  int t = threadIdx.x, blk = blockIdx.x;
  for (int i = t; i < NB; i += 256) h[i] = 0;
  __syncthreads();
  int e0 = blk * EPB, e1 = min(NE, e0 + EPB);
  for (int e = e0 + t; e < e1; e += 256) atomicAdd(&h[ei[NE + e] >> 7], 1);
  __syncthreads();
  for (int i = t; i < NB; i += 256) ghist[i * NBLK + blk] = h[i];
}

__global__ __launch_bounds__(256) void k_scan1g(int* __restrict__ data, int* __restrict__ bsums) {
  __shared__ int sh[256];
  int t = threadIdx.x;
  int base = blockIdx.x * 1024 + t * 4;
  int4 v = *reinterpret_cast<const int4*>(data + base);
  int s = v.x + v.y + v.z + v.w;
  sh[t] = s;
  __syncthreads();
  for (int o = 1; o < 256; o <<= 1) {
    int x = (t >= o) ? sh[t - o] : 0;
    __syncthreads();
    sh[t] += x;
    __syncthreads();
  }
  int ex = sh[t] - s;
  int4 o4;
  o4.x = ex; o4.y = ex + v.x; o4.z = ex + v.x + v.y; o4.w = ex + v.x + v.y + v.z;
  *reinterpret_cast<int4*>(data + base) = o4;
  if (t == 255) bsums[blockIdx.x] = sh[255];
}

__global__ __launch_bounds__(512) void k_scan2(int* bsums, int nb) {
  __shared__ int sh[512];
  int t = threadIdx.x;
  int v = (t < nb) ? bsums[t] : 0;
  sh[t] = v;
  __syncthreads();
  for (int o = 1; o < 512; o <<= 1) {
    int x = (t >= o) ? sh[t - o] : 0;
    __syncthreads();
    sh[t] += x;
    __syncthreads();
  }
  if (t < nb) bsums[t] = sh[t] - v;   // exclusive
}

__global__ __launch_bounds__(256) void k_scan3g(int* __restrict__ data, const int* __restrict__ bsums) {
  int t = threadIdx.x;
  int base = blockIdx.x * 1024 + t * 4;
  int add = bsums[blockIdx.x];
  int4 v = *reinterpret_cast<int4*>(data + base);
  v.x += add; v.y += add; v.z += add; v.w += add;
  *reinterpret_cast<int4*>(data + base) = v;
}

__global__ __launch_bounds__(256) void k_scatter(const int* __restrict__ ei, const int* __restrict__ ghist,
                                                 int2* __restrict__ tmp) {
  __shared__ int cur[NB];
  int t = threadIdx.x, blk = blockIdx.x;
  for (int i = t; i < NB; i += 256) cur[i] = ghist[i * NBLK + blk];
  __syncthreads();
  int e0 = blk * EPB, e1 = min(NE, e0 + EPB);
  for (int e = e0 + t; e < e1; e += 256) {
    int d = ei[NE + e], s = ei[e];
    int p = atomicAdd(&cur[d >> 7], 1);   // LDS atomic (fast, block-local)
    tmp[p] = make_int2(d, s);
  }
}

__global__ __launch_bounds__(256) void k_fine(const int2* __restrict__ tmp, const int* __restrict__ ghist,
                                              int* __restrict__ deg, int* __restrict__ offs,
                                              float* __restrict__ dis, int* __restrict__ csr) {
  __shared__ int fh[128], fsc[128], fc[128];
  int b = blockIdx.x, t = threadIdx.x;
  int bs = ghist[b * NBLK];
  int be = (b + 1 < NB) ? ghist[(b + 1) * NBLK] : NE;
  if (t < 128) fh[t] = 0;
  __syncthreads();
  for (int e = bs + t; e < be; e += 256) atomicAdd(&fh[tmp[e].x & 127], 1);
  __syncthreads();
  if (t < 128) fsc[t] = fh[t];
  __syncthreads();
  for (int o = 1; o < 128; o <<= 1) {
    int x = 0;
    if (t < 128 && t >= o) x = fsc[t - o];
    __syncthreads();
    if (t < 128) fsc[t] += x;
    __syncthreads();
  }
  if (t < 128) {
    int ex = fsc[t] - fh[t];
    int node = b * 128 + t;
    fc[t] = bs + ex;
    if (node < NN) {
      deg[node] = fh[t];
      offs[node] = bs + ex;
      dis[node] = rsqrtf((float)(fh[t] + 1));   // +1 self-loop
    }
  }
  __syncthreads();
  for (int e = bs + t; e < be; e += 256) {
    int2 ds = tmp[e];
    int p = atomicAdd(&fc[ds.x & 127], 1);
    csr[p] = ds.y;
  }
}

__global__ __launch_bounds__(256) void k_zero(float* p, int n) {
  int i = blockIdx.x * 256 + threadIdx.x;
  if (i < n) p[i] = 0.f;
}

// ---------------- W pre-pack: fragment-major bf16 B-operand ----------------
// WF[(n*4+ks)*64 + lane][j] = W[k][col], col = n*16 + (lane&15), k = ks*32 + (lane>>4)*8 + j
__global__ __launch_bounds__(256) void k_prepw(const float* __restrict__ W, ushort* __restrict__ WF) {
  int t = blockIdx.x * 256 + threadIdx.x;
  if (t >= 2048) return;
  int lane = t & 63, nk = t >> 6;
  int n = nk >> 2, ks = nk & 3;
  int col = n * 16 + (lane & 15);
  int k0 = ks * 32 + (lane >> 4) * 8;
#pragma unroll
  for (int j = 0; j < 8; ++j) WF[(size_t)t * 8 + j] = f2b(W[(k0 + j) * NH + col]);
}

// ---------------- MFMA GEMM: hs = (norm?(X) @ W) * dis  (bf16 out) ----------------
// Wave = 16 rows x 128 cols. Block = 4 waves = 64 rows. No LDS.
template <bool NORM>
__global__ __launch_bounds__(256) void k_gemm(const void* __restrict__ Xv, const ushort* __restrict__ WF,
                                              const float* __restrict__ dis, const int* __restrict__ batch,
                                              const float* __restrict__ Aaff, const float* __restrict__ Baff,
                                              ushort* __restrict__ out) {
  int t = threadIdx.x;
  int w = t >> 6, lane = t & 63;
  int r0 = blockIdx.x * 64 + w * 16;
  int arow = r0 + (lane & 15);
  int khi = lane >> 4;                    // 0..3
  int arowc = (arow < NN) ? arow : (NN - 1);

  f32x4 acc[8];
#pragma unroll
  for (int n = 0; n < 8; ++n) acc[n] = (f32x4){0.f, 0.f, 0.f, 0.f};

  int g = 0;
  if (NORM) g = batch[arowc];
  const bf16x8* WFv = reinterpret_cast<const bf16x8*>(WF);

#pragma unroll
  for (int ks = 0; ks < 4; ++ks) {
    int k0 = ks * 32 + khi * 8;
    bf16x8 a;
    if (!NORM) {
      const float* X = (const float*)Xv;
      float4 x0 = *reinterpret_cast<const float4*>(X + (size_t)arowc * NH + k0);
      float4 x1 = *reinterpret_cast<const float4*>(X + (size_t)arowc * NH + k0 + 4);
      a[0] = (short)f2b(x0.x); a[1] = (short)f2b(x0.y); a[2] = (short)f2b(x0.z); a[3] = (short)f2b(x0.w);
      a[4] = (short)f2b(x1.x); a[5] = (short)f2b(x1.y); a[6] = (short)f2b(x1.z); a[7] = (short)f2b(x1.w);
    } else {
      const ushort* X = (const ushort*)Xv;
      bf16x8 xr = *reinterpret_cast<const bf16x8*>(X + (size_t)arowc * NH + k0);
      float4 A0 = *reinterpret_cast<const float4*>(Aaff + g * NH + k0);
      float4 A1 = *reinterpret_cast<const float4*>(Aaff + g * NH + k0 + 4);
      float4 B0 = *reinterpret_cast<const float4*>(Baff + g * NH + k0);
      float4 B1 = *reinterpret_cast<const float4*>(Baff + g * NH + k0 + 4);
      a[0] = (short)f2b(fmaf(A0.x, b2f((ushort)xr[0]), B0.x));
      a[1] = (short)f2b(fmaf(A0.y, b2f((ushort)xr[1]), B0.y));
      a[2] = (short)f2b(fmaf(A0.z, b2f((ushort)xr[2]), B0.z));
      a[3] = (short)f2b(fmaf(A0.w, b2f((ushort)xr[3]), B0.w));
      a[4] = (short)f2b(fmaf(A1.x, b2f((ushort)xr[4]), B1.x));
      a[5] = (short)f2b(fmaf(A1.y, b2f((ushort)xr[5]), B1.y));
      a[6] = (short)f2b(fmaf(A1.z, b2f((ushort)xr[6]), B1.z));
      a[7] = (short)f2b(fmaf(A1.w, b2f((ushort)xr[7]), B1.w));
    }
#pragma unroll
    for (int n = 0; n < 8; ++n) {
      bf16x8 b = WFv[(n * 4 + ks) * 64 + lane];
      acc[n] = __builtin_amdgcn_mfma_f32_16x16x32_bf16(a, b, acc[n], 0, 0, 0);
    }
  }

  // D: col = n*16 + (lane&15), row = r0 + khi*4 + reg
  int colb = lane & 15;
#pragma unroll
  for (int reg = 0; reg < 4; ++reg) {
    int row = r0 + khi * 4 + reg;
    if (row < NN) {
      float d = dis[row];
#pragma unroll
      for (int n = 0; n < 8; ++n)
        out[(size_t)row * NH + n * 16 + colb] = f2b(acc[n][reg] * d);
    }
  }
}

// ---------------- aggregation: t = relu(dis[i]*(hs[i]+sum_src hs[src]) + b), bf16 in/out ----------------
__global__ __launch_bounds__(256) void k_agg(const ushort* __restrict__ hs, const int* __restrict__ offs,
                                             const int* __restrict__ deg, const int* __restrict__ csr,
                                             const float* __restrict__ dis, const float* __restrict__ bias,
                                             ushort* __restrict__ out) {
  int wv = threadIdx.x >> 6, lane = threadIdx.x & 63;
  int node = blockIdx.x * 4 + wv;
  if (node >= NN) return;
  const uint* hs2 = reinterpret_cast<const uint*>(hs);
  uint self = hs2[(size_t)node * 64 + lane];
  float ax = lo2f(self), ay = hi2f(self);
  int beg = offs[node], cnt = deg[node];
  int i = 0;
  for (; i + 4 <= cnt; i += 4) {
    int s0 = csr[beg + i], s1 = csr[beg + i + 1], s2 = csr[beg + i + 2], s3 = csr[beg + i + 3];
    uint v0 = hs2[(size_t)s0 * 64 + lane];
    uint v1 = hs2[(size_t)s1 * 64 + lane];
    uint v2 = hs2[(size_t)s2 * 64 + lane];
    uint v3 = hs2[(size_t)s3 * 64 + lane];
    ax += lo2f(v0) + lo2f(v1) + lo2f(v2) + lo2f(v3);
    ay += hi2f(v0) + hi2f(v1) + hi2f(v2) + hi2f(v3);
  }
  for (; i < cnt; ++i) {
    uint v = hs2[(size_t)csr[beg + i] * 64 + lane];
    ax += lo2f(v);
    ay += hi2f(v);
  }
  float d = dis[node];
  int f = lane * 2;
  float ox = fmaxf(fmaf(d, ax, bias[f]), 0.f);
  float oy = fmaxf(fmaf(d, ay, bias[f + 1]), 0.f);
  uint packed = (uint)f2b(ox) | ((uint)f2b(oy) << 16);
  reinterpret_cast<uint*>(out)[(size_t)node * 64 + lane] = packed;
}

// ---------------- GraphNorm stats: per-(g,f) sum & sumsq (bf16 input) ----------------
__global__ __launch_bounds__(256) void k_stats(const ushort* __restrict__ t1, const int* __restrict__ gstart,
                                               float* __restrict__ acc) {
  int g = blockIdx.x >> 4, s = blockIdx.x & 15;
  int beg = gstart[g], end = gstart[g + 1];
  int f2 = threadIdx.x & 63, q = threadIdx.x >> 6;   // 4 row-groups
  const uint* t2 = reinterpret_cast<const uint*>(t1);
  float sx = 0.f, qx = 0.f, sy = 0.f, qy = 0.f;
  for (int n = beg + s * 4 + q; n < end; n += 64) {
    uint v = t2[(size_t)n * 64 + f2];
    float a = lo2f(v), b = hi2f(v);
    sx += a; qx = fmaf(a, a, qx);
    sy += b; qy = fmaf(b, b, qy);
  }
  __shared__ float sh[4][256];
  sh[0][threadIdx.x] = sx; sh[1][threadIdx.x] = qx;
  sh[2][threadIdx.x] = sy; sh[3][threadIdx.x] = qy;
  __syncthreads();
  if (q == 0) {
#pragma unroll
    for (int qq = 1; qq < 4; ++qq) {
      int idx = (qq << 6) | f2;
      sx += sh[0][idx]; qx += sh[1][idx];
      sy += sh[2][idx]; qy += sh[3][idx];
    }
    int f = f2 * 2;
    atomicAdd(&acc[g * NH + f], sx);
    atomicAdd(&acc[g * NH + f + 1], sy);
    atomicAdd(&acc[NG * NH + g * NH + f], qx);
    atomicAdd(&acc[NG * NH + g * NH + f + 1], qy);
  }
}

__global__ __launch_bounds__(128) void k_fin1(const float* __restrict__ acc, const int* __restrict__ counts,
                                              const float* __restrict__ gw, const float* __restrict__ gb,
                                              const float* __restrict__ ga,
                                              float* __restrict__ Aaff, float* __restrict__ Baff) {
  int g = blockIdx.x, f = threadIdx.x;
  float cnt = fmaxf((float)counts[g], 1.f);
  float m = acc[g * NH + f] / cnt;
  float ex2 = acc[NG * NH + g * NH + f] / cnt;
  float a = ga[f];
  float var = ex2 - 2.f * a * m * m + a * a * m * m;
  float rstd = rsqrtf(var + EPSV);
  float A = gw[f] * rstd;
  Aaff[g * NH + f] = A;
  Baff[g * NH + f] = gb[f] - A * a * m;
}

__global__ __launch_bounds__(128) void k_fin2(const float* __restrict__ acc, const int* __restrict__ counts,
                                              const float* __restrict__ gw, const float* __restrict__ gb,
                                              const float* __restrict__ ga,
                                              float* __restrict__ pooled) {
  int g = blockIdx.x, f = threadIdx.x;
  float cnt = fmaxf((float)counts[g], 1.f);
  float m = acc[g * NH + f] / cnt;
  float ex2 = acc[NG * NH + g * NH + f] / cnt;
  float a = ga[f];
  float var = ex2 - 2.f * a * m * m + a * a * m * m;
  float rstd = rsqrtf(var + EPSV);
  pooled[g * NH + f] = gw[f] * rstd * (m - a * m) + gb[f];
}

__global__ __launch_bounds__(64) void k_head(const float* __restrict__ pooled, const float* __restrict__ Wc,
                                             const float* __restrict__ bc, float* __restrict__ outp) {
  int g = blockIdx.x, t = threadIdx.x;
  __shared__ float lg[NC];
  if (t < NC) {
    float s = bc[t];
    for (int h = 0; h < NH; ++h) s = fmaf(pooled[g * NH + h], Wc[h * NC + t], s);
    lg[t] = s;
  }
  __syncthreads();
  if (t == 0) {
    float mx = lg[0];
    for (int c = 1; c < NC; ++c) mx = fmaxf(mx, lg[c]);
    float ex[NC];
    float sum = 0.f;
    for (int c = 0; c < NC; ++c) { ex[c] = __expf(lg[c] - mx); sum += ex[c]; }
    float inv = 1.f / sum;
    for (int c = 0; c < NC; ++c) outp[g * NC + c] = ex[c] * inv;
  }
}

// ---------------- launch ----------------
extern "C" void kernel_launch(void* const* d_in, const int* in_sizes, int n_in,
                              void* d_out, int out_size, void* d_ws, size_t ws_size,
                              hipStream_t stream) {
  const float* x   = (const float*)d_in[0];
  const int*   ei  = (const int*)d_in[1];
  const int*   bat = (const int*)d_in[2];
  const float* W1  = (const float*)d_in[3];
  const float* b1  = (const float*)d_in[4];
  const float* gw1 = (const float*)d_in[5];
  const float* gb1 = (const float*)d_in[6];
  const float* ga1 = (const float*)d_in[7];
  const float* W2  = (const float*)d_in[8];
  const float* b2  = (const float*)d_in[9];
  const float* gw2 = (const float*)d_in[10];
  const float* gb2 = (const float*)d_in[11];
  const float* ga2 = (const float*)d_in[12];
  const float* Wc  = (const float*)d_in[13];
  const float* bc  = (const float*)d_in[14];
  float* outp = (float*)d_out;

  char* ws = (char*)d_ws;
  size_t off = 0;
  auto alloc = [&](size_t b) { size_t p = off; off += (b + 255) & ~(size_t)255; return p; };
  int*    deg     = (int*)(ws + alloc((size_t)NN * 4));
  float*  dis     = (float*)(ws + alloc((size_t)NN * 4));
  int*    counts  = (int*)(ws + alloc(NG * 4));
  int*    gstart  = (int*)(ws + alloc((NG + 1) * 4));
  int*    offs    = (int*)(ws + alloc((size_t)NN * 4));
  int*    bsums   = (int*)(ws + alloc(512 * 4));
  int*    csr     = (int*)(ws + alloc((size_t)NE * 4));
  float*  statacc = (float*)(ws + alloc((size_t)2 * NG * NH * 4));
  float*  Aaff    = (float*)(ws + alloc((size_t)NG * NH * 4));
  float*  Baff    = (float*)(ws + alloc((size_t)NG * NH * 4));
  float*  pooled  = (float*)(ws + alloc((size_t)NG * NH * 4));
  ushort* WF1     = (ushort*)(ws + alloc((size_t)2048 * 8 * 2));
  ushort* WF2     = (ushort*)(ws + alloc((size_t)2048 * 8 * 2));
  ushort* bufA    = (ushort*)(ws + alloc((size_t)NN * NH * 2));
  ushort* bufB    = (ushort*)(ws + alloc((size_t)NN * NH * 2));
  // sort temps alias bufA (dead before first k_gemm writes bufA): 12.8+1.6 MB <= 25.6 MB
  int2* tmp   = (int2*)bufA;
  int*  ghist = (int*)((char*)bufA + (((size_t)NE * 8 + 255) & ~(size_t)255));
  (void)ws_size; (void)in_sizes; (void)n_in; (void)out_size;

  int nstat = 2 * NG * NH;

  // prep: counts/gstart via binary search (batch sorted); CSR via counting sort
  k_gstart2<<<1, 128, 0, stream>>>(bat, gstart, counts);
  k_hist<<<NBLK, 256, 0, stream>>>(ei, ghist);
  k_scan1g<<<NSB, 256, 0, stream>>>(ghist, bsums);
  k_scan2<<<1, 512, 0, stream>>>(bsums, NSB);
  k_scan3g<<<NSB, 256, 0, stream>>>(ghist, bsums);
  k_scatter<<<NBLK, 256, 0, stream>>>(ei, ghist, tmp);
  k_fine<<<NB, 256, 0, stream>>>(tmp, ghist, deg, offs, dis, csr);
  k_prepw<<<8, 256, 0, stream>>>(W1, WF1);
  k_prepw<<<8, 256, 0, stream>>>(W2, WF2);

  int gemm_grid = (NN + 63) / 64;   // 1563

  // layer 1
  k_zero<<<(nstat + 255) / 256, 256, 0, stream>>>(statacc, nstat);
  k_gemm<false><<<gemm_grid, 256, 0, stream>>>(x, WF1, dis, bat, nullptr, nullptr, bufA);
  k_agg<<<(NN + 3) / 4, 256, 0, stream>>>(bufA, offs, deg, csr, dis, b1, bufB);
  k_stats<<<NG * 16, 256, 0, stream>>>(bufB, gstart, statacc);
  k_fin1<<<NG, 128, 0, stream>>>(statacc, counts, gw1, gb1, ga1, Aaff, Baff);

  // layer 2 (norm fused into GEMM A-fragment load)
  k_zero<<<(nstat + 255) / 256, 256, 0, stream>>>(statacc, nstat);
  k_gemm<true><<<gemm_grid, 256, 0, stream>>>(bufB, WF2, dis, bat, Aaff, Baff, bufA);
  k_agg<<<(NN + 3) / 4, 256, 0, stream>>>(bufA, offs, deg, csr, dis, b2, bufB);
  k_stats<<<NG * 16, 256, 0, stream>>>(bufB, gstart, statacc);
  k_fin2<<<NG, 128, 0, stream>>>(statacc, counts, gw2, gb2, ga2, pooled);

  k_head<<<NG, 64, 0, stream>>>(pooled, Wc, bc, outp);
}